// Round 1
// baseline (294.236 us; speedup 1.0000x reference)
//
#include <hip/hip_runtime.h>

// ---------------------------------------------------------------------------
// QTranBase: twin 3-layer MLPs via bf16 MFMA (m97-verified gemm_bt structure)
//   Q: relu([states|actions] @ Qw1 + b1) -> relu(@Qw2 + b2) -> @Qw3 + b3
//   V: relu(states @ Vw1 + b1)           -> relu(@Vw2 + b2) -> @Vw3 + b3
// Layer-3 fused into layer-2 epilogue (shuffle-reduce + atomicAdd).
// ---------------------------------------------------------------------------

#define ROWS 32768
#define EMBED 512

using frag_ab = __attribute__((ext_vector_type(8))) short;   // 8 x bf16
using f32x4   = __attribute__((ext_vector_type(4))) float;   // MFMA C/D

__device__ __forceinline__ unsigned short f2bf(float f) {
    // round-to-nearest-even truncation to bf16 (inputs are sane, no NaN care)
    unsigned int u = __builtin_bit_cast(unsigned int, f);
    return (unsigned short)((u + 0x7fffu + ((u >> 16) & 1u)) >> 16);
}

__device__ __forceinline__ void async_copy16(const void* g, void* l) {
    // dest = wave-uniform LDS base; HW writes base + lane*16
    __builtin_amdgcn_global_load_lds(
        (const __attribute__((address_space(1))) unsigned int*)g,
        (__attribute__((address_space(3))) unsigned int*)l, 16, 0, 0);
}

// --- out[i] = (i < ROWS) ? Qb3 : Vb3  (layer-3 bias pre-seeded for atomics)
__global__ void init_out(float* __restrict__ out,
                         const float* __restrict__ qb3,
                         const float* __restrict__ vb3) {
    int i = blockIdx.x * 256 + threadIdx.x;
    out[i] = (i < ROWS) ? qb3[0] : vb3[0];
}

// --- X[m][0:512] = bf16(states[m]);  X[m][512:1024] = bf16(actions[m])
__global__ void convert_x(const float* __restrict__ states,
                          const float* __restrict__ actions,
                          unsigned short* __restrict__ X) {
    size_t t = (size_t)blockIdx.x * 256 + threadIdx.x;   // 8 elems per thread
    int m   = (int)(t >> 7);          // 128 chunks of 8 per 1024-wide row
    int col = (int)(t & 127) * 8;
    const float* src = (col < 512) ? states + (size_t)m * 512 + col
                                   : actions + (size_t)m * 512 + (col - 512);
    float4 a = *(const float4*)src;
    float4 b = *(const float4*)(src + 4);
    uint4 o;
    o.x = (unsigned)f2bf(a.x) | ((unsigned)f2bf(a.y) << 16);
    o.y = (unsigned)f2bf(a.z) | ((unsigned)f2bf(a.w) << 16);
    o.z = (unsigned)f2bf(b.x) | ((unsigned)f2bf(b.y) << 16);
    o.w = (unsigned)f2bf(b.z) | ((unsigned)f2bf(b.w) << 16);
    *(uint4*)(X + (size_t)m * 1024 + col) = o;
}

// --- Wt[n][k] = bf16(W[k][n]) for the four big weight matrices
__global__ void prep_w(const float* __restrict__ Qw1, const float* __restrict__ Qw2,
                       const float* __restrict__ Vw1, const float* __restrict__ Vw2,
                       unsigned short* __restrict__ Qw1t, unsigned short* __restrict__ Qw2t,
                       unsigned short* __restrict__ Vw1t, unsigned short* __restrict__ Vw2t) {
    int t = blockIdx.x * 256 + threadIdx.x;
    if (t < 512 * 1024) {                      // Qw1: [1024][512] -> [512][1024]
        int n = t >> 10, k = t & 1023;
        Qw1t[t] = f2bf(Qw1[(size_t)k * 512 + n]);
    } else {
        t -= 512 * 1024;
        int seg = t >> 18;                     // 262144-element segments
        int r = t & 0x3ffff;
        int n = r >> 9, k = r & 511;
        const float* W = (seg == 0) ? Qw2 : (seg == 1) ? Vw1 : Vw2;
        unsigned short* O = (seg == 0) ? Qw2t : (seg == 1) ? Vw1t : Vw2t;
        O[r] = f2bf(W[(size_t)k * 512 + n]);
    }
}

// ---------------------------------------------------------------------------
// C = relu(A @ Wt^T + bias) ; A:[M][lda] bf16 row-major, Wt:[N][K] bf16.
// BM=BN=128, BK=32, 256 threads = 4 waves (2x2 of 64x64), 16x16x32 MFMA.
// FUSE: epilogue computes out[row] += sum_n relu(h[n]) * w3[n] via atomics.
// ---------------------------------------------------------------------------
template <bool FUSE>
__global__ __launch_bounds__(256, 2)
void gemm_bt(const unsigned short* __restrict__ A, int lda,
             const unsigned short* __restrict__ Wt, int K,
             const float* __restrict__ bias,
             unsigned short* __restrict__ H,
             const float* __restrict__ w3, float* __restrict__ out) {
    __shared__ __align__(16) unsigned short As[128 * 32];   // 8 KB
    __shared__ __align__(16) unsigned short Bs[128 * 32];   // 8 KB

    const int tid  = threadIdx.x;
    const int wave = tid >> 6, lane = tid & 63;
    const int bm = blockIdx.x * 128, bn = blockIdx.y * 128;
    const int wm = (wave & 1) * 64, wn = (wave >> 1) * 64;
    const int lrow = lane & 15, quad = lane >> 4;

    f32x4 acc[4][4] = {};

    // staging geometry: linear byte = t*4096 + wave*1024 + lane*16
    const int lin  = wave * 1024 + lane * 16;
    const int rowS = lin >> 6;              // 64 B per 32-elem bf16 row
    const int colS = (lin & 63) >> 1;       // element offset within row

    const unsigned short* gA0 = A  + (size_t)(bm + rowS)      * lda + colS;
    const unsigned short* gA1 = A  + (size_t)(bm + rowS + 64) * lda + colS;
    const unsigned short* gB0 = Wt + (size_t)(bn + rowS)      * K   + colS;
    const unsigned short* gB1 = Wt + (size_t)(bn + rowS + 64) * K   + colS;
    unsigned short* ldsA0 = As + wave * 512;          // wave-uniform bases
    unsigned short* ldsA1 = As + 2048 + wave * 512;
    unsigned short* ldsB0 = Bs + wave * 512;
    unsigned short* ldsB1 = Bs + 2048 + wave * 512;

    for (int k0 = 0; k0 < K; k0 += 32) {
        async_copy16(gA0, ldsA0);
        async_copy16(gA1, ldsA1);
        async_copy16(gB0, ldsB0);
        async_copy16(gB1, ldsB1);
        gA0 += 32; gA1 += 32; gB0 += 32; gB1 += 32;
        __syncthreads();   // drains vmcnt (compiler emits full waitcnt)

        frag_ab af[4], bfr[4];
#pragma unroll
        for (int i = 0; i < 4; i++)
            af[i] = *(const frag_ab*)&As[(wm + i * 16 + lrow) * 32 + quad * 8];
#pragma unroll
        for (int j = 0; j < 4; j++)
            bfr[j] = *(const frag_ab*)&Bs[(wn + j * 16 + lrow) * 32 + quad * 8];
#pragma unroll
        for (int i = 0; i < 4; i++)
#pragma unroll
            for (int j = 0; j < 4; j++)
                acc[i][j] = __builtin_amdgcn_mfma_f32_16x16x32_bf16(
                    af[i], bfr[j], acc[i][j], 0, 0, 0);
        __syncthreads();
    }

    if (!FUSE) {
        // H[row][col] = bf16(relu(acc + bias[col])), H is [M][512]
#pragma unroll
        for (int j = 0; j < 4; j++) {
            const int col = bn + wn + j * 16 + lrow;
            const float bc = bias[col];
#pragma unroll
            for (int i = 0; i < 4; i++) {
                const int row0 = bm + wm + i * 16 + quad * 4;
#pragma unroll
                for (int r = 0; r < 4; r++) {
                    float v = acc[i][j][r] + bc;
                    v = v > 0.0f ? v : 0.0f;
                    H[(size_t)(row0 + r) * EMBED + col] = f2bf(v);
                }
            }
        }
    } else {
        // out[row] += sum_cols relu(acc + bias) * w3[col]
        float bc[4], wc[4];
#pragma unroll
        for (int j = 0; j < 4; j++) {
            const int col = bn + wn + j * 16 + lrow;
            bc[j] = bias[col];
            wc[j] = w3[col];
        }
#pragma unroll
        for (int i = 0; i < 4; i++) {
#pragma unroll
            for (int r = 0; r < 4; r++) {
                float s = 0.0f;
#pragma unroll
                for (int j = 0; j < 4; j++) {
                    float v = acc[i][j][r] + bc[j];
                    v = v > 0.0f ? v : 0.0f;
                    s += v * wc[j];
                }
                // reduce across the 16 lanes of this quad (same output row)
#pragma unroll
                for (int m = 1; m < 16; m <<= 1) s += __shfl_xor(s, m, 64);
                if (lrow == 0)
                    atomicAdd(&out[bm + wm + i * 16 + quad * 4 + r], s);
            }
        }
    }
}

extern "C" void kernel_launch(void* const* d_in, const int* in_sizes, int n_in,
                              void* d_out, int out_size, void* d_ws, size_t ws_size,
                              hipStream_t stream) {
    const float* states  = (const float*)d_in[0];
    const float* actions = (const float*)d_in[1];
    const float* Qw1 = (const float*)d_in[2];
    const float* Qb1 = (const float*)d_in[3];
    const float* Qw2 = (const float*)d_in[4];
    const float* Qb2 = (const float*)d_in[5];
    const float* Qw3 = (const float*)d_in[6];
    const float* Qb3 = (const float*)d_in[7];
    const float* Vw1 = (const float*)d_in[8];
    const float* Vb1 = (const float*)d_in[9];
    const float* Vw2 = (const float*)d_in[10];
    const float* Vb2 = (const float*)d_in[11];
    const float* Vw3 = (const float*)d_in[12];
    const float* Vb3 = (const float*)d_in[13];
    float* out = (float*)d_out;

    // workspace layout (bytes)
    char* ws = (char*)d_ws;
    unsigned short* X    = (unsigned short*)ws;                        // 64 MB
    unsigned short* h1Q  = (unsigned short*)(ws + 67108864);           // 32 MB
    unsigned short* h1V  = (unsigned short*)(ws + 100663296);          // 32 MB
    unsigned short* Qw1t = (unsigned short*)(ws + 134217728);          // 1 MB
    unsigned short* Qw2t = Qw1t + 512 * 1024;                          // 512 KB
    unsigned short* Vw1t = Qw2t + 512 * 512;
    unsigned short* Vw2t = Vw1t + 512 * 512;

    init_out<<<dim3(256), dim3(256), 0, stream>>>(out, Qb3, Vb3);
    convert_x<<<dim3(16384), dim3(256), 0, stream>>>(states, actions, X);
    prep_w<<<dim3(5120), dim3(256), 0, stream>>>(Qw1, Qw2, Vw1, Vw2,
                                                 Qw1t, Qw2t, Vw1t, Vw2t);

    dim3 grid(ROWS / 128, EMBED / 128);   // 256 x 4
    // Q layer1: K=1024 over X=[states|actions]
    gemm_bt<false><<<grid, 256, 0, stream>>>(X, 1024, Qw1t, 1024, Qb1, h1Q, nullptr, nullptr);
    // V layer1: K=512 over first 512 cols of X (states), lda=1024
    gemm_bt<false><<<grid, 256, 0, stream>>>(X, 1024, Vw1t, 512, Vb1, h1V, nullptr, nullptr);
    // layer2 + fused layer3
    gemm_bt<true><<<grid, 256, 0, stream>>>(h1Q, 512, Qw2t, 512, Qb2, nullptr, Qw3, out);
    gemm_bt<true><<<grid, 256, 0, stream>>>(h1V, 512, Vw2t, 512, Vb2, nullptr, Vw3, out + ROWS);
}